// Round 1
// baseline (1593.933 us; speedup 1.0000x reference)
//
#include <hip/hip_runtime.h>
#include <math.h>

// GCN 2-layer (1->8->1) collapsed to scalar form:
//   deg[d] = #edges into d (+1 self-loop); dinv = 1/sqrt(deg)
//   a[d]   = sum_e dinv[s]*dinv[d]*x[s]  + dinv[d]^2*x[d]
//   h2[i]  = sum_j relu(a[i]*W1[j]+b1[j])*W2[j]
//   out[d] = sum_e dinv[s]*dinv[d]*h2[s] + dinv[d]^2*h2[i] + b2

__global__ void k_zero(float* __restrict__ deg_a, float* __restrict__ out, int N) {
    int i = blockIdx.x * blockDim.x + threadIdx.x;
    if (i < 2 * N) deg_a[i] = 0.0f;
    if (i < N) out[i] = 0.0f;
}

__global__ void k_deg(const int* __restrict__ dst, int E, int E4,
                      float* __restrict__ deg) {
    int t = blockIdx.x * blockDim.x + threadIdx.x;
    if (t < E4) {
        int4 d = reinterpret_cast<const int4*>(dst)[t];
        atomicAdd(&deg[d.x], 1.0f);
        atomicAdd(&deg[d.y], 1.0f);
        atomicAdd(&deg[d.z], 1.0f);
        atomicAdd(&deg[d.w], 1.0f);
    }
    int rem = E - E4 * 4;
    if (t < rem) atomicAdd(&deg[dst[E4 * 4 + t]], 1.0f);
}

__global__ void k_dinv(const float* __restrict__ deg, float* __restrict__ dinv, int N) {
    int i = blockIdx.x * blockDim.x + threadIdx.x;
    if (i < N) dinv[i] = 1.0f / sqrtf(deg[i] + 1.0f);  // +1 self-loop; deg>=1 always
}

__global__ void k_scatter1(const int* __restrict__ src, const int* __restrict__ dst,
                           const float* __restrict__ x, const float* __restrict__ dinv,
                           float* __restrict__ a, int E, int E4) {
    int t = blockIdx.x * blockDim.x + threadIdx.x;
    if (t < E4) {
        int4 s = reinterpret_cast<const int4*>(src)[t];
        int4 d = reinterpret_cast<const int4*>(dst)[t];
        atomicAdd(&a[d.x], dinv[s.x] * dinv[d.x] * x[s.x]);
        atomicAdd(&a[d.y], dinv[s.y] * dinv[d.y] * x[s.y]);
        atomicAdd(&a[d.z], dinv[s.z] * dinv[d.z] * x[s.z]);
        atomicAdd(&a[d.w], dinv[s.w] * dinv[d.w] * x[s.w]);
    }
    int rem = E - E4 * 4;
    if (t < rem) {
        int s = src[E4 * 4 + t], d = dst[E4 * 4 + t];
        atomicAdd(&a[d], dinv[s] * dinv[d] * x[s]);
    }
}

__global__ void k_h2(const float* __restrict__ a, const float* __restrict__ x,
                     const float* __restrict__ dinv,
                     const float* __restrict__ W1, const float* __restrict__ b1,
                     const float* __restrict__ W2,
                     float* __restrict__ h2, int N) {
    int i = blockIdx.x * blockDim.x + threadIdx.x;
    if (i < N) {
        float di = dinv[i];
        float at = a[i] + di * di * x[i];  // self-loop term of layer-1 aggregation
        float acc = 0.0f;
#pragma unroll
        for (int j = 0; j < 8; ++j) {
            float v = fmaxf(at * W1[j] + b1[j], 0.0f);
            acc += v * W2[j];
        }
        h2[i] = acc;
    }
}

__global__ void k_scatter2(const int* __restrict__ src, const int* __restrict__ dst,
                           const float* __restrict__ h2, const float* __restrict__ dinv,
                           float* __restrict__ out, int E, int E4) {
    int t = blockIdx.x * blockDim.x + threadIdx.x;
    if (t < E4) {
        int4 s = reinterpret_cast<const int4*>(src)[t];
        int4 d = reinterpret_cast<const int4*>(dst)[t];
        atomicAdd(&out[d.x], dinv[s.x] * dinv[d.x] * h2[s.x]);
        atomicAdd(&out[d.y], dinv[s.y] * dinv[d.y] * h2[s.y]);
        atomicAdd(&out[d.z], dinv[s.z] * dinv[d.z] * h2[s.z]);
        atomicAdd(&out[d.w], dinv[s.w] * dinv[d.w] * h2[s.w]);
    }
    int rem = E - E4 * 4;
    if (t < rem) {
        int s = src[E4 * 4 + t], d = dst[E4 * 4 + t];
        atomicAdd(&out[d], dinv[s] * dinv[d] * h2[s]);
    }
}

__global__ void k_finalize(const float* __restrict__ h2, const float* __restrict__ dinv,
                           const float* __restrict__ b2, float* __restrict__ out, int N) {
    int i = blockIdx.x * blockDim.x + threadIdx.x;
    if (i < N) {
        float di = dinv[i];
        out[i] += di * di * h2[i] + b2[0];
    }
}

extern "C" void kernel_launch(void* const* d_in, const int* in_sizes, int n_in,
                              void* d_out, int out_size, void* d_ws, size_t ws_size,
                              hipStream_t stream) {
    const float* x  = (const float*)d_in[0];
    const int*   ei = (const int*)d_in[1];   // [2, E] int32
    const float* W1 = (const float*)d_in[2]; // [1,8]
    const float* b1 = (const float*)d_in[3]; // [8]
    const float* W2 = (const float*)d_in[4]; // [8,1]
    const float* b2 = (const float*)d_in[5]; // [1]
    float* out = (float*)d_out;

    int N = in_sizes[0];
    int E = in_sizes[1] / 2;
    const int* src = ei;
    const int* dst = ei + E;

    float* ws   = (float*)d_ws;
    float* deg  = ws;                    // [N]
    float* a    = ws + (size_t)N;        // [N]   (deg,a adjacent: one zero region)
    float* dinv = ws + 2 * (size_t)N;    // [N]
    float* h2   = ws + 3 * (size_t)N;    // [N]

    const int TB = 256;
    int E4 = E / 4;
    int egrid = (E4 + TB - 1) / TB;
    if (egrid < 1) egrid = 1;
    int ngrid = (N + TB - 1) / TB;
    int zgrid = (2 * N + TB - 1) / TB;

    // zero deg, a, out (ws/out are poisoned 0xAA before every launch)
    k_zero<<<zgrid, TB, 0, stream>>>(deg, out, N);
    k_deg<<<egrid, TB, 0, stream>>>(dst, E, E4, deg);
    k_dinv<<<ngrid, TB, 0, stream>>>(deg, dinv, N);
    k_scatter1<<<egrid, TB, 0, stream>>>(src, dst, x, dinv, a, E, E4);
    k_h2<<<ngrid, TB, 0, stream>>>(a, x, dinv, W1, b1, W2, h2, N);
    k_scatter2<<<egrid, TB, 0, stream>>>(src, dst, h2, dinv, out, E, E4);
    k_finalize<<<ngrid, TB, 0, stream>>>(h2, dinv, b2, out, N);
}

// Round 3
// 1578.095 us; speedup vs baseline: 1.0100x; 1.0100x over previous
//
#include <hip/hip_runtime.h>
#include <math.h>

// GCN 2-layer (1->8->1), collapsed + factored form:
//   deg[d]  = #edges into d; dinv = 1/sqrt(deg+1)           (self-loop)
//   v[i]    = dinv[i]*x[i]
//   acc1[d] = sum_e v[src[e]]          (single random gather + atomic per edge)
//   at[i]   = dinv[i]*(acc1[i] + v[i]) (deferred dinv[d] factor + self-loop)
//   h2[i]   = sum_j relu(at[i]*W1[j]+b1[j])*W2[j];  u[i] = dinv[i]*h2[i]
//   acc2[d] = sum_e u[src[e]]  (into out)
//   out[d]  = dinv[d]*(acc2[d] + u[d]) + b2

typedef int  vint4  __attribute__((ext_vector_type(4)));  // clang vector: NT-load OK

__global__ void k_zero(float* __restrict__ deg_acc, float* __restrict__ out, int N) {
    int i = blockIdx.x * blockDim.x + threadIdx.x;
    if (i < 2 * N) deg_acc[i] = 0.0f;
    if (i < N) out[i] = 0.0f;
}

__global__ void k_deg(const int* __restrict__ dst, int E, int E4,
                      float* __restrict__ deg) {
    int t = blockIdx.x * blockDim.x + threadIdx.x;
    if (t < E4) {
        vint4 d = __builtin_nontemporal_load(reinterpret_cast<const vint4*>(dst) + t);
        atomicAdd(&deg[d.x], 1.0f);
        atomicAdd(&deg[d.y], 1.0f);
        atomicAdd(&deg[d.z], 1.0f);
        atomicAdd(&deg[d.w], 1.0f);
    }
    int rem = E - E4 * 4;
    if (t < rem) atomicAdd(&deg[dst[E4 * 4 + t]], 1.0f);
}

// dinv[i] = rsqrt(deg+1); v[i] = dinv[i]*x[i]   (all coalesced)
__global__ void k_dinv(const float* __restrict__ deg, const float* __restrict__ x,
                       float* __restrict__ dinv, float* __restrict__ v, int N) {
    int i = blockIdx.x * blockDim.x + threadIdx.x;
    if (i < N) {
        float di = 1.0f / sqrtf(deg[i] + 1.0f);
        dinv[i] = di;
        v[i] = di * x[i];
    }
}

// acc[d] += v[s] : one random gather + one random atomic per edge
__global__ void k_scatter(const int* __restrict__ src, const int* __restrict__ dst,
                          const float* __restrict__ v, float* __restrict__ acc,
                          int E, int E4) {
    int t = blockIdx.x * blockDim.x + threadIdx.x;
    if (t < E4) {
        vint4 s = __builtin_nontemporal_load(reinterpret_cast<const vint4*>(src) + t);
        vint4 d = __builtin_nontemporal_load(reinterpret_cast<const vint4*>(dst) + t);
        atomicAdd(&acc[d.x], v[s.x]);
        atomicAdd(&acc[d.y], v[s.y]);
        atomicAdd(&acc[d.z], v[s.z]);
        atomicAdd(&acc[d.w], v[s.w]);
    }
    int rem = E - E4 * 4;
    if (t < rem) {
        int s = src[E4 * 4 + t], d = dst[E4 * 4 + t];
        atomicAdd(&acc[d], v[s]);
    }
}

// at = dinv*(acc1 + v); h2 = MLP(at); u = dinv*h2   (all coalesced)
__global__ void k_h2(const float* __restrict__ acc1, const float* __restrict__ v,
                     const float* __restrict__ dinv,
                     const float* __restrict__ W1, const float* __restrict__ b1,
                     const float* __restrict__ W2,
                     float* __restrict__ u, int N) {
    int i = blockIdx.x * blockDim.x + threadIdx.x;
    if (i < N) {
        float di = dinv[i];
        float at = di * (acc1[i] + v[i]);
        float acc = 0.0f;
#pragma unroll
        for (int j = 0; j < 8; ++j) {
            float t = fmaxf(at * W1[j] + b1[j], 0.0f);
            acc += t * W2[j];
        }
        u[i] = di * acc;
    }
}

// out[d] = dinv[d]*(acc2[d] + u[d]) + b2   (acc2 accumulated in-place in out)
__global__ void k_finalize(const float* __restrict__ u, const float* __restrict__ dinv,
                           const float* __restrict__ b2, float* __restrict__ out, int N) {
    int i = blockIdx.x * blockDim.x + threadIdx.x;
    if (i < N) {
        out[i] = dinv[i] * (out[i] + u[i]) + b2[0];
    }
}

extern "C" void kernel_launch(void* const* d_in, const int* in_sizes, int n_in,
                              void* d_out, int out_size, void* d_ws, size_t ws_size,
                              hipStream_t stream) {
    const float* x  = (const float*)d_in[0];
    const int*   ei = (const int*)d_in[1];   // [2, E] int32
    const float* W1 = (const float*)d_in[2]; // [1,8]
    const float* b1 = (const float*)d_in[3]; // [8]
    const float* W2 = (const float*)d_in[4]; // [8,1]
    const float* b2 = (const float*)d_in[5]; // [1]
    float* out = (float*)d_out;

    int N = in_sizes[0];
    int E = in_sizes[1] / 2;
    const int* src = ei;
    const int* dst = ei + E;

    float* ws   = (float*)d_ws;
    float* deg  = ws;                    // [N]  \ zeroed together
    float* acc1 = ws + (size_t)N;        // [N]  /
    float* dinv = ws + 2 * (size_t)N;    // [N]
    float* v    = ws + 3 * (size_t)N;    // [N]  layer-1 premultiplied values
    float* u    = ws + 4 * (size_t)N;    // [N]  layer-2 premultiplied values

    const int TB = 256;
    int E4 = E / 4;
    int egrid = (E4 + TB - 1) / TB;
    if (egrid < 1) egrid = 1;
    int ngrid = (N + TB - 1) / TB;
    int zgrid = (2 * N + TB - 1) / TB;

    k_zero<<<zgrid, TB, 0, stream>>>(deg, out, N);
    k_deg<<<egrid, TB, 0, stream>>>(dst, E, E4, deg);
    k_dinv<<<ngrid, TB, 0, stream>>>(deg, x, dinv, v, N);
    k_scatter<<<egrid, TB, 0, stream>>>(src, dst, v, acc1, E, E4);
    k_h2<<<ngrid, TB, 0, stream>>>(acc1, v, dinv, W1, b1, W2, u, N);
    k_scatter<<<egrid, TB, 0, stream>>>(src, dst, u, out, E, E4);
    k_finalize<<<ngrid, TB, 0, stream>>>(u, dinv, b2, out, N);
}

// Round 4
// 650.975 us; speedup vs baseline: 2.4485x; 2.4242x over previous
//
#include <hip/hip_runtime.h>
#include <math.h>

// GCN 2-layer (1->8->1), collapsed + factored + dst-binned (zero global atomics).
//
// Math (verified round 1/3):
//   deg[d]  = #edges into d; dinv = rsqrt(deg+1)            (self-loop)
//   v[i]    = dinv[i]*x[i]
//   acc1[d] = sum_e v[src[e]]
//   at[i]   = dinv[i]*(acc1[i] + v[i])
//   u[i]    = dinv[i] * sum_j relu(at[i]*W1[j]+b1[j])*W2[j]
//   out[d]  = dinv[d]*(acc2[d] + u[d]) + b2,  acc2[d] = sum_e u[src[e]]
//
// Binning: bucket b = dst>>8 (256 nodes/bucket -> 1KB LDS accumulator window).
// Counting sort: per-chunk histogram -> per-bucket column scan -> bucket base
// scan -> exact placement with LDS cursors. Record = ((dst&255)<<20)|src
// (requires N <= 2^20; N = 1e6 here).

#define CHUNK 65536   // edges per sort block (256 thr x 256)
#define HB    4096    // LDS histogram capacity (>= NB)

// ---- pass 1: per-chunk bucket histogram (row-major: cnt[chunk][bucket]) ----
__global__ __launch_bounds__(256) void k_hist(const int* __restrict__ dst, int E,
                                              int NB, int* __restrict__ cnt) {
    __shared__ int h[HB];
    for (int i = threadIdx.x; i < NB; i += 256) h[i] = 0;
    __syncthreads();
    long s0 = (long)blockIdx.x * CHUNK;
    int end = (int)min((long)CHUNK, (long)E - s0);
    for (int k = threadIdx.x; k < end; k += 256)
        atomicAdd(&h[((unsigned)dst[s0 + k]) >> 8], 1);
    __syncthreads();
    int* row = cnt + (size_t)blockIdx.x * NB;
    for (int b = threadIdx.x; b < NB; b += 256) row[b] = h[b];
}

// ---- pass 2: exclusive scan down each bucket column; total per bucket ----
__global__ __launch_bounds__(256) void k_scan_cols(int* __restrict__ cnt, int NB,
                                                   int NBLK, int* __restrict__ total) {
    int b = blockIdx.x * blockDim.x + threadIdx.x;
    if (b >= NB) return;
    int sum = 0;
    for (int j = 0; j < NBLK; ++j) {
        size_t idx = (size_t)j * NB + b;
        int c = cnt[idx];
        cnt[idx] = sum;
        sum += c;
    }
    total[b] = sum;
}

// ---- pass 3: exclusive scan of bucket totals -> base[NB+1] (1 block) ----
__global__ __launch_bounds__(256) void k_scan_base(const int* __restrict__ total,
                                                   int NB, int* __restrict__ base) {
    __shared__ int part[256];
    int t = threadIdx.x;
    int loc[16];
    int sum = 0;
#pragma unroll
    for (int i = 0; i < 16; ++i) {
        int b = t * 16 + i;
        int val = (b < NB) ? total[b] : 0;
        loc[i] = sum;
        sum += val;
    }
    part[t] = sum;
    __syncthreads();
    for (int off = 1; off < 256; off <<= 1) {
        int v = (t >= off) ? part[t - off] : 0;
        __syncthreads();
        part[t] += v;
        __syncthreads();
    }
    int mybase = (t > 0) ? part[t - 1] : 0;
#pragma unroll
    for (int i = 0; i < 16; ++i) {
        int b = t * 16 + i;
        if (b < NB) base[b] = mybase + loc[i];
    }
    if (t == 255) base[NB] = part[255];
}

// ---- pass 4: place records at exact slots (LDS cursors, no global atomics) ----
__global__ __launch_bounds__(256) void k_bin(const int* __restrict__ src,
                                             const int* __restrict__ dst, int E, int NB,
                                             const int* __restrict__ cnt,
                                             const int* __restrict__ base,
                                             int* __restrict__ recs) {
    __shared__ int cur[HB];
    const int* row = cnt + (size_t)blockIdx.x * NB;
    for (int b = threadIdx.x; b < NB; b += 256) cur[b] = base[b] + row[b];
    __syncthreads();
    long s0 = (long)blockIdx.x * CHUNK;
    int end = (int)min((long)CHUNK, (long)E - s0);
    for (int k = threadIdx.x; k < end; k += 256) {
        int d = dst[s0 + k];
        int s = src[s0 + k];
        int slot = atomicAdd(&cur[((unsigned)d) >> 8], 1);
        recs[slot] = ((d & 255) << 20) | s;
    }
}

// ---- pass 5: per-bucket deg count -> dinv, v (block per bucket) ----
__global__ __launch_bounds__(256) void k_degv(const int* __restrict__ recs,
                                              const int* __restrict__ base,
                                              const float* __restrict__ x,
                                              float* __restrict__ dinv,
                                              float* __restrict__ v, int N) {
    __shared__ int c[256];
    int t = threadIdx.x;
    c[t] = 0;
    __syncthreads();
    int lo = base[blockIdx.x], hi = base[blockIdx.x + 1];
    for (int i = lo + t; i < hi; i += 256)
        atomicAdd(&c[((unsigned)recs[i]) >> 20], 1);
    __syncthreads();
    int node = blockIdx.x * 256 + t;
    if (node < N) {
        float di = rsqrtf((float)c[t] + 1.0f);
        dinv[node] = di;
        v[node] = di * x[node];
    }
}

// ---- pass 6: layer-1 gather/LDS-scatter + fused MLP -> u ----
__global__ __launch_bounds__(256) void k_gs1(const int* __restrict__ recs,
                                             const int* __restrict__ base,
                                             const float* __restrict__ v,
                                             const float* __restrict__ dinv,
                                             const float* __restrict__ W1,
                                             const float* __restrict__ b1,
                                             const float* __restrict__ W2,
                                             float* __restrict__ u, int N) {
    __shared__ float acc[256];
    int t = threadIdx.x;
    acc[t] = 0.0f;
    __syncthreads();
    int lo = base[blockIdx.x], hi = base[blockIdx.x + 1];
    int i = lo + t;
    // 4-deep manual unroll to keep gathers in flight
    for (; i + 768 < hi; i += 1024) {
        int r0 = recs[i], r1 = recs[i + 256], r2 = recs[i + 512], r3 = recs[i + 768];
        float v0 = v[r0 & 0xFFFFF], v1 = v[r1 & 0xFFFFF];
        float v2 = v[r2 & 0xFFFFF], v3 = v[r3 & 0xFFFFF];
        atomicAdd(&acc[((unsigned)r0) >> 20], v0);
        atomicAdd(&acc[((unsigned)r1) >> 20], v1);
        atomicAdd(&acc[((unsigned)r2) >> 20], v2);
        atomicAdd(&acc[((unsigned)r3) >> 20], v3);
    }
    for (; i < hi; i += 256) {
        int r = recs[i];
        atomicAdd(&acc[((unsigned)r) >> 20], v[r & 0xFFFFF]);
    }
    __syncthreads();
    int node = blockIdx.x * 256 + t;
    if (node < N) {
        float di = dinv[node];
        float at = di * (acc[t] + v[node]);
        float s = 0.0f;
#pragma unroll
        for (int j = 0; j < 8; ++j)
            s += fmaxf(at * W1[j] + b1[j], 0.0f) * W2[j];
        u[node] = di * s;
    }
}

// ---- pass 7: layer-2 gather/LDS-scatter + fused finalize -> out ----
__global__ __launch_bounds__(256) void k_gs2(const int* __restrict__ recs,
                                             const int* __restrict__ base,
                                             const float* __restrict__ u,
                                             const float* __restrict__ dinv,
                                             const float* __restrict__ b2,
                                             float* __restrict__ out, int N) {
    __shared__ float acc[256];
    int t = threadIdx.x;
    acc[t] = 0.0f;
    __syncthreads();
    int lo = base[blockIdx.x], hi = base[blockIdx.x + 1];
    int i = lo + t;
    for (; i + 768 < hi; i += 1024) {
        int r0 = recs[i], r1 = recs[i + 256], r2 = recs[i + 512], r3 = recs[i + 768];
        float v0 = u[r0 & 0xFFFFF], v1 = u[r1 & 0xFFFFF];
        float v2 = u[r2 & 0xFFFFF], v3 = u[r3 & 0xFFFFF];
        atomicAdd(&acc[((unsigned)r0) >> 20], v0);
        atomicAdd(&acc[((unsigned)r1) >> 20], v1);
        atomicAdd(&acc[((unsigned)r2) >> 20], v2);
        atomicAdd(&acc[((unsigned)r3) >> 20], v3);
    }
    for (; i < hi; i += 256) {
        int r = recs[i];
        atomicAdd(&acc[((unsigned)r) >> 20], u[r & 0xFFFFF]);
    }
    __syncthreads();
    int node = blockIdx.x * 256 + t;
    if (node < N)
        out[node] = dinv[node] * (acc[t] + u[node]) + b2[0];
}

extern "C" void kernel_launch(void* const* d_in, const int* in_sizes, int n_in,
                              void* d_out, int out_size, void* d_ws, size_t ws_size,
                              hipStream_t stream) {
    const float* x  = (const float*)d_in[0];
    const int*   ei = (const int*)d_in[1];   // [2, E] int32
    const float* W1 = (const float*)d_in[2];
    const float* b1 = (const float*)d_in[3];
    const float* W2 = (const float*)d_in[4];
    const float* b2 = (const float*)d_in[5];
    float* out = (float*)d_out;

    int N = in_sizes[0];
    int E = in_sizes[1] / 2;
    const int* src = ei;
    const int* dst = ei + E;

    int NB   = (N + 255) >> 8;            // buckets of 256 nodes (<= 4096 for N<=2^20)
    int NBLK = (E + CHUNK - 1) / CHUNK;   // sort chunks

    // workspace layout (4B units)
    char* w = (char*)d_ws;
    float* dinv  = (float*)w;                         w += sizeof(float) * (size_t)N;
    float* v     = (float*)w;                         w += sizeof(float) * (size_t)N;
    float* u     = (float*)w;                         w += sizeof(float) * (size_t)N;
    int*   cnt   = (int*)w;                           w += sizeof(int) * (size_t)NBLK * NB;
    int*   total = (int*)w;                           w += sizeof(int) * (size_t)(NB + 1);
    int*   base  = (int*)w;                           w += sizeof(int) * (size_t)(NB + 1);
    int*   recs  = (int*)w;                           w += sizeof(int) * (size_t)E;

    k_hist     <<<NBLK, 256, 0, stream>>>(dst, E, NB, cnt);
    k_scan_cols<<<(NB + 255) / 256, 256, 0, stream>>>(cnt, NB, NBLK, total);
    k_scan_base<<<1, 256, 0, stream>>>(total, NB, base);
    k_bin      <<<NBLK, 256, 0, stream>>>(src, dst, E, NB, cnt, base, recs);
    k_degv     <<<NB, 256, 0, stream>>>(recs, base, x, dinv, v, N);
    k_gs1      <<<NB, 256, 0, stream>>>(recs, base, v, dinv, W1, b1, W2, u, N);
    k_gs2      <<<NB, 256, 0, stream>>>(recs, base, u, dinv, b2, out, N);
}

// Round 5
// 574.095 us; speedup vs baseline: 2.7764x; 1.1339x over previous
//
#include <hip/hip_runtime.h>
#include <math.h>

// GCN 2-layer (1->8->1), collapsed + factored + dst-binned (zero global atomics).
//
// Math (verified):
//   deg[d]  = #edges into d; dinv = rsqrt(deg+1)            (self-loop)
//   v[i]    = dinv[i]*x[i]
//   acc1[d] = sum_e v[src[e]]
//   at[i]   = dinv[i]*(acc1[i] + v[i])
//   u[i]    = dinv[i] * sum_j relu(at[i]*W1[j]+b1[j])*W2[j]
//   out[d]  = dinv[d]*(acc2[d] + u[d]) + b2,  acc2[d] = sum_e u[src[e]]
//
// Binning: bucket b = dst>>8 (256 nodes/bucket -> 1KB LDS accumulator window).
// Counting sort: per-chunk histogram -> column scan -> base scan -> placement.
// Record = ((dst&255)<<20)|src  (requires N <= 2^20; N = 1e6 here).
// Round-5 change: CHUNK 65536->16384, 512-thr sort blocks (occupancy was 6.7%),
// int4 NT edge loads, NT recs loads in bucket passes.

typedef int vint4 __attribute__((ext_vector_type(4)));

#define HB    4096    // LDS histogram/cursor capacity (>= NB)
#define STHR  512     // sort-pass block size

// ---- pass 1: per-chunk bucket histogram (row-major: cnt[chunk][bucket]) ----
__global__ __launch_bounds__(STHR) void k_hist(const int* __restrict__ dst, int E,
                                               int NB, int chunk, int* __restrict__ cnt) {
    __shared__ int h[HB];
    for (int i = threadIdx.x; i < NB; i += STHR) h[i] = 0;
    __syncthreads();
    long s0 = (long)blockIdx.x * chunk;
    int end = (int)min((long)chunk, (long)E - s0);
    const vint4* p = reinterpret_cast<const vint4*>(dst + s0);
    int n4 = end >> 2;
    for (int k = threadIdx.x; k < n4; k += STHR) {
        vint4 d = __builtin_nontemporal_load(p + k);
        atomicAdd(&h[((unsigned)d.x) >> 8], 1);
        atomicAdd(&h[((unsigned)d.y) >> 8], 1);
        atomicAdd(&h[((unsigned)d.z) >> 8], 1);
        atomicAdd(&h[((unsigned)d.w) >> 8], 1);
    }
    for (int k = (n4 << 2) + threadIdx.x; k < end; k += STHR)
        atomicAdd(&h[((unsigned)dst[s0 + k]) >> 8], 1);
    __syncthreads();
    int* row = cnt + (size_t)blockIdx.x * NB;
    for (int b = threadIdx.x; b < NB; b += STHR) row[b] = h[b];
}

// ---- pass 2: exclusive scan down each bucket column; total per bucket ----
__global__ __launch_bounds__(256) void k_scan_cols(int* __restrict__ cnt, int NB,
                                                   int NBLK, int* __restrict__ total) {
    int b = blockIdx.x * blockDim.x + threadIdx.x;
    if (b >= NB) return;
    int sum = 0;
    for (int j = 0; j < NBLK; ++j) {
        size_t idx = (size_t)j * NB + b;
        int c = cnt[idx];
        cnt[idx] = sum;
        sum += c;
    }
    total[b] = sum;
}

// ---- pass 3: exclusive scan of bucket totals -> base[NB+1] (1 block) ----
__global__ __launch_bounds__(256) void k_scan_base(const int* __restrict__ total,
                                                   int NB, int* __restrict__ base) {
    __shared__ int part[256];
    int t = threadIdx.x;
    int loc[16];
    int sum = 0;
#pragma unroll
    for (int i = 0; i < 16; ++i) {
        int b = t * 16 + i;
        int val = (b < NB) ? total[b] : 0;
        loc[i] = sum;
        sum += val;
    }
    part[t] = sum;
    __syncthreads();
    for (int off = 1; off < 256; off <<= 1) {
        int v = (t >= off) ? part[t - off] : 0;
        __syncthreads();
        part[t] += v;
        __syncthreads();
    }
    int mybase = (t > 0) ? part[t - 1] : 0;
#pragma unroll
    for (int i = 0; i < 16; ++i) {
        int b = t * 16 + i;
        if (b < NB) base[b] = mybase + loc[i];
    }
    if (t == 255) base[NB] = part[255];
}

// ---- pass 4: place records at exact slots (LDS cursors, no global atomics) ----
__global__ __launch_bounds__(STHR) void k_bin(const int* __restrict__ src,
                                              const int* __restrict__ dst, int E, int NB,
                                              int chunk, const int* __restrict__ cnt,
                                              const int* __restrict__ base,
                                              int* __restrict__ recs) {
    __shared__ int cur[HB];
    const int* row = cnt + (size_t)blockIdx.x * NB;
    for (int b = threadIdx.x; b < NB; b += STHR) cur[b] = base[b] + row[b];
    __syncthreads();
    long s0 = (long)blockIdx.x * chunk;
    int end = (int)min((long)chunk, (long)E - s0);
    const vint4* ps = reinterpret_cast<const vint4*>(src + s0);
    const vint4* pd = reinterpret_cast<const vint4*>(dst + s0);
    int n4 = end >> 2;
    for (int k = threadIdx.x; k < n4; k += STHR) {
        vint4 s = __builtin_nontemporal_load(ps + k);
        vint4 d = __builtin_nontemporal_load(pd + k);
        int slot;
        slot = atomicAdd(&cur[((unsigned)d.x) >> 8], 1); recs[slot] = ((d.x & 255) << 20) | s.x;
        slot = atomicAdd(&cur[((unsigned)d.y) >> 8], 1); recs[slot] = ((d.y & 255) << 20) | s.y;
        slot = atomicAdd(&cur[((unsigned)d.z) >> 8], 1); recs[slot] = ((d.z & 255) << 20) | s.z;
        slot = atomicAdd(&cur[((unsigned)d.w) >> 8], 1); recs[slot] = ((d.w & 255) << 20) | s.w;
    }
    for (int k = (n4 << 2) + threadIdx.x; k < end; k += STHR) {
        int d = dst[s0 + k], s = src[s0 + k];
        int slot = atomicAdd(&cur[((unsigned)d) >> 8], 1);
        recs[slot] = ((d & 255) << 20) | s;
    }
}

// ---- pass 5: per-bucket deg count -> dinv, v (block per bucket) ----
__global__ __launch_bounds__(256) void k_degv(const int* __restrict__ recs,
                                              const int* __restrict__ base,
                                              const float* __restrict__ x,
                                              float* __restrict__ dinv,
                                              float* __restrict__ v, int N) {
    __shared__ int c[256];
    int t = threadIdx.x;
    c[t] = 0;
    __syncthreads();
    int lo = base[blockIdx.x], hi = base[blockIdx.x + 1];
    for (int i = lo + t; i < hi; i += 256)
        atomicAdd(&c[((unsigned)__builtin_nontemporal_load(recs + i)) >> 20], 1);
    __syncthreads();
    int node = blockIdx.x * 256 + t;
    if (node < N) {
        float di = rsqrtf((float)c[t] + 1.0f);
        dinv[node] = di;
        v[node] = di * x[node];
    }
}

// ---- pass 6: layer-1 gather/LDS-scatter + fused MLP -> u ----
__global__ __launch_bounds__(256) void k_gs1(const int* __restrict__ recs,
                                             const int* __restrict__ base,
                                             const float* __restrict__ v,
                                             const float* __restrict__ dinv,
                                             const float* __restrict__ W1,
                                             const float* __restrict__ b1,
                                             const float* __restrict__ W2,
                                             float* __restrict__ u, int N) {
    __shared__ float acc[256];
    int t = threadIdx.x;
    acc[t] = 0.0f;
    __syncthreads();
    int lo = base[blockIdx.x], hi = base[blockIdx.x + 1];
    int i = lo + t;
    for (; i + 768 < hi; i += 1024) {
        int r0 = __builtin_nontemporal_load(recs + i);
        int r1 = __builtin_nontemporal_load(recs + i + 256);
        int r2 = __builtin_nontemporal_load(recs + i + 512);
        int r3 = __builtin_nontemporal_load(recs + i + 768);
        float v0 = v[r0 & 0xFFFFF], v1 = v[r1 & 0xFFFFF];
        float v2 = v[r2 & 0xFFFFF], v3 = v[r3 & 0xFFFFF];
        atomicAdd(&acc[((unsigned)r0) >> 20], v0);
        atomicAdd(&acc[((unsigned)r1) >> 20], v1);
        atomicAdd(&acc[((unsigned)r2) >> 20], v2);
        atomicAdd(&acc[((unsigned)r3) >> 20], v3);
    }
    for (; i < hi; i += 256) {
        int r = __builtin_nontemporal_load(recs + i);
        atomicAdd(&acc[((unsigned)r) >> 20], v[r & 0xFFFFF]);
    }
    __syncthreads();
    int node = blockIdx.x * 256 + t;
    if (node < N) {
        float di = dinv[node];
        float at = di * (acc[t] + v[node]);
        float s = 0.0f;
#pragma unroll
        for (int j = 0; j < 8; ++j)
            s += fmaxf(at * W1[j] + b1[j], 0.0f) * W2[j];
        u[node] = di * s;
    }
}

// ---- pass 7: layer-2 gather/LDS-scatter + fused finalize -> out ----
__global__ __launch_bounds__(256) void k_gs2(const int* __restrict__ recs,
                                             const int* __restrict__ base,
                                             const float* __restrict__ u,
                                             const float* __restrict__ dinv,
                                             const float* __restrict__ b2,
                                             float* __restrict__ out, int N) {
    __shared__ float acc[256];
    int t = threadIdx.x;
    acc[t] = 0.0f;
    __syncthreads();
    int lo = base[blockIdx.x], hi = base[blockIdx.x + 1];
    int i = lo + t;
    for (; i + 768 < hi; i += 1024) {
        int r0 = __builtin_nontemporal_load(recs + i);
        int r1 = __builtin_nontemporal_load(recs + i + 256);
        int r2 = __builtin_nontemporal_load(recs + i + 512);
        int r3 = __builtin_nontemporal_load(recs + i + 768);
        float v0 = u[r0 & 0xFFFFF], v1 = u[r1 & 0xFFFFF];
        float v2 = u[r2 & 0xFFFFF], v3 = u[r3 & 0xFFFFF];
        atomicAdd(&acc[((unsigned)r0) >> 20], v0);
        atomicAdd(&acc[((unsigned)r1) >> 20], v1);
        atomicAdd(&acc[((unsigned)r2) >> 20], v2);
        atomicAdd(&acc[((unsigned)r3) >> 20], v3);
    }
    for (; i < hi; i += 256) {
        int r = __builtin_nontemporal_load(recs + i);
        atomicAdd(&acc[((unsigned)r) >> 20], u[r & 0xFFFFF]);
    }
    __syncthreads();
    int node = blockIdx.x * 256 + t;
    if (node < N)
        out[node] = dinv[node] * (acc[t] + u[node]) + b2[0];
}

extern "C" void kernel_launch(void* const* d_in, const int* in_sizes, int n_in,
                              void* d_out, int out_size, void* d_ws, size_t ws_size,
                              hipStream_t stream) {
    const float* x  = (const float*)d_in[0];
    const int*   ei = (const int*)d_in[1];   // [2, E] int32
    const float* W1 = (const float*)d_in[2];
    const float* b1 = (const float*)d_in[3];
    const float* W2 = (const float*)d_in[4];
    const float* b2 = (const float*)d_in[5];
    float* out = (float*)d_out;

    int N = in_sizes[0];
    int E = in_sizes[1] / 2;
    const int* src = ei;
    const int* dst = ei + E;

    int NB = (N + 255) >> 8;                 // buckets of 256 nodes (<= 4096 for N<=2^20)

    // pick CHUNK: small for occupancy, doubled until workspace fits
    int chunk = 16384;
    long nblk;
    size_t need;
    for (;;) {
        nblk = ((long)E + chunk - 1) / chunk;
        need = sizeof(float) * 3ul * N                 // dinv, v, u
             + sizeof(int) * (size_t)nblk * NB         // cnt
             + sizeof(int) * 2ul * (NB + 1)            // total, base
             + sizeof(int) * (size_t)E;                // recs
        if (need <= ws_size || chunk >= E) break;
        chunk <<= 1;
    }
    int NBLK = (int)nblk;

    char* w = (char*)d_ws;
    float* dinv  = (float*)w;  w += sizeof(float) * (size_t)N;
    float* v     = (float*)w;  w += sizeof(float) * (size_t)N;
    float* u     = (float*)w;  w += sizeof(float) * (size_t)N;
    int*   cnt   = (int*)w;    w += sizeof(int) * (size_t)NBLK * NB;
    int*   total = (int*)w;    w += sizeof(int) * (size_t)(NB + 1);
    int*   base  = (int*)w;    w += sizeof(int) * (size_t)(NB + 1);
    int*   recs  = (int*)w;    w += sizeof(int) * (size_t)E;

    k_hist     <<<NBLK, STHR, 0, stream>>>(dst, E, NB, chunk, cnt);
    k_scan_cols<<<(NB + 255) / 256, 256, 0, stream>>>(cnt, NB, NBLK, total);
    k_scan_base<<<1, 256, 0, stream>>>(total, NB, base);
    k_bin      <<<NBLK, STHR, 0, stream>>>(src, dst, E, NB, chunk, cnt, base, recs);
    k_degv     <<<NB, 256, 0, stream>>>(recs, base, x, dinv, v, N);
    k_gs1      <<<NB, 256, 0, stream>>>(recs, base, v, dinv, W1, b1, W2, u, N);
    k_gs2      <<<NB, 256, 0, stream>>>(recs, base, u, dinv, b2, out, N);
}

// Round 6
// 544.006 us; speedup vs baseline: 2.9300x; 1.0553x over previous
//
#include <hip/hip_runtime.h>
#include <math.h>

// GCN 2-layer (1->8->1), collapsed + factored + dst-binned (zero global atomics).
//
// Math (verified):
//   deg[d]  = #edges into d; dinv = rsqrt(deg+1)            (self-loop)
//   v[i]    = dinv[i]*x[i]
//   acc1[d] = sum_e v[src[e]]
//   at[i]   = dinv[i]*(acc1[i] + v[i])
//   u[i]    = dinv[i] * sum_j relu(at[i]*W1[j]+b1[j])*W2[j]
//   out[d]  = dinv[d]*(acc2[d] + u[d]) + b2,  acc2[d] = sum_e u[src[e]]
//
// Binning: bucket b = dst>>10 (1024 nodes/bucket -> 4KB LDS window).
// Round-6 change: bucket 256->1024 nodes. Write-amp knob is CHUNK/NB records
// per bucket per block: was ~4 rec (17B, always-partial 64B lines, 7x amp,
// 283MB writes); now ~17 rec (68B, 1-2 lines, ~2x amp predicted).
// Record = ((dst&1023)<<20)|src  (requires N <= 2^20; N = 1e6 here).

typedef int vint4 __attribute__((ext_vector_type(4)));

#define HB    1024    // LDS histogram/cursor capacity (>= NB)
#define STHR  512     // sort-pass block size
#define BSH   10      // bucket shift (1024 nodes)
#define BMASK 1023

// ---- pass 1: per-chunk bucket histogram (row-major: cnt[chunk][bucket]) ----
__global__ __launch_bounds__(STHR) void k_hist(const int* __restrict__ dst, int E,
                                               int NB, int chunk, int* __restrict__ cnt) {
    __shared__ int h[HB];
    for (int i = threadIdx.x; i < NB; i += STHR) h[i] = 0;
    __syncthreads();
    long s0 = (long)blockIdx.x * chunk;
    int end = (int)min((long)chunk, (long)E - s0);
    const vint4* p = reinterpret_cast<const vint4*>(dst + s0);
    int n4 = end >> 2;
    for (int k = threadIdx.x; k < n4; k += STHR) {
        vint4 d = __builtin_nontemporal_load(p + k);
        atomicAdd(&h[((unsigned)d.x) >> BSH], 1);
        atomicAdd(&h[((unsigned)d.y) >> BSH], 1);
        atomicAdd(&h[((unsigned)d.z) >> BSH], 1);
        atomicAdd(&h[((unsigned)d.w) >> BSH], 1);
    }
    for (int k = (n4 << 2) + threadIdx.x; k < end; k += STHR)
        atomicAdd(&h[((unsigned)dst[s0 + k]) >> BSH], 1);
    __syncthreads();
    int* row = cnt + (size_t)blockIdx.x * NB;
    for (int b = threadIdx.x; b < NB; b += STHR) row[b] = h[b];
}

// ---- pass 2: exclusive scan down each bucket column; total per bucket ----
__global__ __launch_bounds__(256) void k_scan_cols(int* __restrict__ cnt, int NB,
                                                   int NBLK, int* __restrict__ total) {
    int b = blockIdx.x * blockDim.x + threadIdx.x;
    if (b >= NB) return;
    int sum = 0;
    for (int j = 0; j < NBLK; ++j) {
        size_t idx = (size_t)j * NB + b;
        int c = cnt[idx];
        cnt[idx] = sum;
        sum += c;
    }
    total[b] = sum;
}

// ---- pass 3: exclusive scan of bucket totals -> base[NB+1] (1 block) ----
__global__ __launch_bounds__(256) void k_scan_base(const int* __restrict__ total,
                                                   int NB, int* __restrict__ base) {
    __shared__ int part[256];
    int t = threadIdx.x;
    int loc[16];
    int sum = 0;
#pragma unroll
    for (int i = 0; i < 16; ++i) {
        int b = t * 16 + i;
        int val = (b < NB) ? total[b] : 0;
        loc[i] = sum;
        sum += val;
    }
    part[t] = sum;
    __syncthreads();
    for (int off = 1; off < 256; off <<= 1) {
        int v = (t >= off) ? part[t - off] : 0;
        __syncthreads();
        part[t] += v;
        __syncthreads();
    }
    int mybase = (t > 0) ? part[t - 1] : 0;
#pragma unroll
    for (int i = 0; i < 16; ++i) {
        int b = t * 16 + i;
        if (b < NB) base[b] = mybase + loc[i];
    }
    if (t == 255) base[NB] = part[255];
}

// ---- pass 4: place records at exact slots (LDS cursors, no global atomics) ----
__global__ __launch_bounds__(STHR) void k_bin(const int* __restrict__ src,
                                              const int* __restrict__ dst, int E, int NB,
                                              int chunk, const int* __restrict__ cnt,
                                              const int* __restrict__ base,
                                              int* __restrict__ recs) {
    __shared__ int cur[HB];
    const int* row = cnt + (size_t)blockIdx.x * NB;
    for (int b = threadIdx.x; b < NB; b += STHR) cur[b] = base[b] + row[b];
    __syncthreads();
    long s0 = (long)blockIdx.x * chunk;
    int end = (int)min((long)chunk, (long)E - s0);
    const vint4* ps = reinterpret_cast<const vint4*>(src + s0);
    const vint4* pd = reinterpret_cast<const vint4*>(dst + s0);
    int n4 = end >> 2;
    for (int k = threadIdx.x; k < n4; k += STHR) {
        vint4 s = __builtin_nontemporal_load(ps + k);
        vint4 d = __builtin_nontemporal_load(pd + k);
        int slot;
        slot = atomicAdd(&cur[((unsigned)d.x) >> BSH], 1); recs[slot] = ((d.x & BMASK) << 20) | s.x;
        slot = atomicAdd(&cur[((unsigned)d.y) >> BSH], 1); recs[slot] = ((d.y & BMASK) << 20) | s.y;
        slot = atomicAdd(&cur[((unsigned)d.z) >> BSH], 1); recs[slot] = ((d.z & BMASK) << 20) | s.z;
        slot = atomicAdd(&cur[((unsigned)d.w) >> BSH], 1); recs[slot] = ((d.w & BMASK) << 20) | s.w;
    }
    for (int k = (n4 << 2) + threadIdx.x; k < end; k += STHR) {
        int d = dst[s0 + k], s = src[s0 + k];
        int slot = atomicAdd(&cur[((unsigned)d) >> BSH], 1);
        recs[slot] = ((d & BMASK) << 20) | s;
    }
}

// ---- pass 5: per-bucket deg count -> dinv, v (block per 1024-node bucket) ----
__global__ __launch_bounds__(256) void k_degv(const int* __restrict__ recs,
                                              const int* __restrict__ base,
                                              const float* __restrict__ x,
                                              float* __restrict__ dinv,
                                              float* __restrict__ v, int N) {
    __shared__ int c[1024];
    int t = threadIdx.x;
#pragma unroll
    for (int j = 0; j < 4; ++j) c[t + 256 * j] = 0;
    __syncthreads();
    int lo = base[blockIdx.x], hi = base[blockIdx.x + 1];
    int i = lo + t;
    for (; i + 768 < hi; i += 1024) {
        int r0 = __builtin_nontemporal_load(recs + i);
        int r1 = __builtin_nontemporal_load(recs + i + 256);
        int r2 = __builtin_nontemporal_load(recs + i + 512);
        int r3 = __builtin_nontemporal_load(recs + i + 768);
        atomicAdd(&c[((unsigned)r0) >> 20], 1);
        atomicAdd(&c[((unsigned)r1) >> 20], 1);
        atomicAdd(&c[((unsigned)r2) >> 20], 1);
        atomicAdd(&c[((unsigned)r3) >> 20], 1);
    }
    for (; i < hi; i += 256)
        atomicAdd(&c[((unsigned)__builtin_nontemporal_load(recs + i)) >> 20], 1);
    __syncthreads();
#pragma unroll
    for (int j = 0; j < 4; ++j) {
        int node = blockIdx.x * 1024 + t + 256 * j;
        if (node < N) {
            float di = rsqrtf((float)c[t + 256 * j] + 1.0f);
            dinv[node] = di;
            v[node] = di * x[node];
        }
    }
}

// ---- pass 6: layer-1 gather/LDS-scatter + fused MLP -> u ----
__global__ __launch_bounds__(256) void k_gs1(const int* __restrict__ recs,
                                             const int* __restrict__ base,
                                             const float* __restrict__ v,
                                             const float* __restrict__ dinv,
                                             const float* __restrict__ W1,
                                             const float* __restrict__ b1,
                                             const float* __restrict__ W2,
                                             float* __restrict__ u, int N) {
    __shared__ float acc[1024];
    int t = threadIdx.x;
#pragma unroll
    for (int j = 0; j < 4; ++j) acc[t + 256 * j] = 0.0f;
    __syncthreads();
    int lo = base[blockIdx.x], hi = base[blockIdx.x + 1];
    int i = lo + t;
    for (; i + 768 < hi; i += 1024) {
        int r0 = __builtin_nontemporal_load(recs + i);
        int r1 = __builtin_nontemporal_load(recs + i + 256);
        int r2 = __builtin_nontemporal_load(recs + i + 512);
        int r3 = __builtin_nontemporal_load(recs + i + 768);
        float v0 = v[r0 & 0xFFFFF], v1 = v[r1 & 0xFFFFF];
        float v2 = v[r2 & 0xFFFFF], v3 = v[r3 & 0xFFFFF];
        atomicAdd(&acc[((unsigned)r0) >> 20], v0);
        atomicAdd(&acc[((unsigned)r1) >> 20], v1);
        atomicAdd(&acc[((unsigned)r2) >> 20], v2);
        atomicAdd(&acc[((unsigned)r3) >> 20], v3);
    }
    for (; i < hi; i += 256) {
        int r = __builtin_nontemporal_load(recs + i);
        atomicAdd(&acc[((unsigned)r) >> 20], v[r & 0xFFFFF]);
    }
    __syncthreads();
#pragma unroll
    for (int j = 0; j < 4; ++j) {
        int node = blockIdx.x * 1024 + t + 256 * j;
        if (node < N) {
            float di = dinv[node];
            float at = di * (acc[t + 256 * j] + v[node]);
            float s = 0.0f;
#pragma unroll
            for (int jj = 0; jj < 8; ++jj)
                s += fmaxf(at * W1[jj] + b1[jj], 0.0f) * W2[jj];
            u[node] = di * s;
        }
    }
}

// ---- pass 7: layer-2 gather/LDS-scatter + fused finalize -> out ----
__global__ __launch_bounds__(256) void k_gs2(const int* __restrict__ recs,
                                             const int* __restrict__ base,
                                             const float* __restrict__ u,
                                             const float* __restrict__ dinv,
                                             const float* __restrict__ b2,
                                             float* __restrict__ out, int N) {
    __shared__ float acc[1024];
    int t = threadIdx.x;
#pragma unroll
    for (int j = 0; j < 4; ++j) acc[t + 256 * j] = 0.0f;
    __syncthreads();
    int lo = base[blockIdx.x], hi = base[blockIdx.x + 1];
    int i = lo + t;
    for (; i + 768 < hi; i += 1024) {
        int r0 = __builtin_nontemporal_load(recs + i);
        int r1 = __builtin_nontemporal_load(recs + i + 256);
        int r2 = __builtin_nontemporal_load(recs + i + 512);
        int r3 = __builtin_nontemporal_load(recs + i + 768);
        float v0 = u[r0 & 0xFFFFF], v1 = u[r1 & 0xFFFFF];
        float v2 = u[r2 & 0xFFFFF], v3 = u[r3 & 0xFFFFF];
        atomicAdd(&acc[((unsigned)r0) >> 20], v0);
        atomicAdd(&acc[((unsigned)r1) >> 20], v1);
        atomicAdd(&acc[((unsigned)r2) >> 20], v2);
        atomicAdd(&acc[((unsigned)r3) >> 20], v3);
    }
    for (; i < hi; i += 256) {
        int r = __builtin_nontemporal_load(recs + i);
        atomicAdd(&acc[((unsigned)r) >> 20], u[r & 0xFFFFF]);
    }
    __syncthreads();
#pragma unroll
    for (int j = 0; j < 4; ++j) {
        int node = blockIdx.x * 1024 + t + 256 * j;
        if (node < N)
            out[node] = dinv[node] * (acc[t + 256 * j] + u[node]) + b2[0];
    }
}

extern "C" void kernel_launch(void* const* d_in, const int* in_sizes, int n_in,
                              void* d_out, int out_size, void* d_ws, size_t ws_size,
                              hipStream_t stream) {
    const float* x  = (const float*)d_in[0];
    const int*   ei = (const int*)d_in[1];   // [2, E] int32
    const float* W1 = (const float*)d_in[2];
    const float* b1 = (const float*)d_in[3];
    const float* W2 = (const float*)d_in[4];
    const float* b2 = (const float*)d_in[5];
    float* out = (float*)d_out;

    int N = in_sizes[0];
    int E = in_sizes[1] / 2;
    const int* src = ei;
    const int* dst = ei + E;

    int NB = (N + BMASK) >> BSH;             // 1024-node buckets (<= 1024 for N<=2^20)

    // pick CHUNK: small for occupancy, doubled until workspace fits
    int chunk = 16384;
    long nblk;
    size_t need;
    for (;;) {
        nblk = ((long)E + chunk - 1) / chunk;
        need = sizeof(float) * 3ul * N                 // dinv, v, u
             + sizeof(int) * (size_t)nblk * NB         // cnt
             + sizeof(int) * 2ul * (NB + 1)            // total, base
             + sizeof(int) * (size_t)E;                // recs
        if (need <= ws_size || chunk >= E) break;
        chunk <<= 1;
    }
    int NBLK = (int)nblk;

    char* w = (char*)d_ws;
    float* dinv  = (float*)w;  w += sizeof(float) * (size_t)N;
    float* v     = (float*)w;  w += sizeof(float) * (size_t)N;
    float* u     = (float*)w;  w += sizeof(float) * (size_t)N;
    int*   cnt   = (int*)w;    w += sizeof(int) * (size_t)NBLK * NB;
    int*   total = (int*)w;    w += sizeof(int) * (size_t)(NB + 1);
    int*   base  = (int*)w;    w += sizeof(int) * (size_t)(NB + 1);
    int*   recs  = (int*)w;    w += sizeof(int) * (size_t)E;

    k_hist     <<<NBLK, STHR, 0, stream>>>(dst, E, NB, chunk, cnt);
    k_scan_cols<<<(NB + 255) / 256, 256, 0, stream>>>(cnt, NB, NBLK, total);
    k_scan_base<<<1, 256, 0, stream>>>(total, NB, base);
    k_bin      <<<NBLK, STHR, 0, stream>>>(src, dst, E, NB, chunk, cnt, base, recs);
    k_degv     <<<NB, 256, 0, stream>>>(recs, base, x, dinv, v, N);
    k_gs1      <<<NB, 256, 0, stream>>>(recs, base, v, dinv, W1, b1, W2, u, N);
    k_gs2      <<<NB, 256, 0, stream>>>(recs, base, u, dinv, b2, out, N);
}

// Round 7
// 352.827 us; speedup vs baseline: 4.5176x; 1.5418x over previous
//
#include <hip/hip_runtime.h>
#include <math.h>

// GCN 2-layer (1->8->1), collapsed + factored + dst-binned (zero global atomics
// on the accumulate paths).
//
// Math (verified):
//   deg[d]  = #edges into d; dinv = rsqrt(deg+1)            (self-loop)
//   v[i]    = dinv[i]*x[i]
//   acc1[d] = sum_e v[src[e]]
//   at[i]   = dinv[i]*(acc1[i] + v[i])
//   u[i]    = dinv[i] * sum_j relu(at[i]*W1[j]+b1[j])*W2[j]
//   out[d]  = dinv[d]*(acc2[d] + u[d]) + b2,  acc2[d] = sum_e u[src[e]]
//
// Round-7: single fused sort kernel (count -> block scan -> bulk global
// reservation -> LDS-staged placement -> coalesced flush). Bucket regions are
// fixed-capacity (C = avg + 8*sqrt(avg), overflow probability ~0 for uniform
// random dst). Record = ((dst&1023)<<20)|src (requires N <= 2^20).
// Write-amp theory: round-6's 5.4x amp came from temporally-dispersed 4B
// stores; staging makes interior lines written densely by one wave.

typedef int vint4 __attribute__((ext_vector_type(4)));

#define HB    1024    // bucket capacity in LDS tables (>= NB)
#define STHR  512     // sort block size (8 waves)
#define CHUNK 16384   // edges per sort block
#define BSH   10      // bucket shift (1024 nodes/bucket)
#define BMASK 1023

__global__ void k_zero_gcur(int* __restrict__ gcur, int NB) {
    int i = blockIdx.x * blockDim.x + threadIdx.x;
    if (i < NB) gcur[i] = 0;
}

// ---- fused counting sort: one block per 16K-edge chunk ----
__global__ __launch_bounds__(STHR) void k_sort(const int* __restrict__ src,
                                               const int* __restrict__ dst,
                                               int E, int NB, int C,
                                               int* __restrict__ gcur,
                                               int* __restrict__ recs) {
    __shared__ int cnt[HB];      // phase A: counts; phase C: cursors
    __shared__ int off[HB + 4];  // exclusive within-block offsets (+ off[NB]=end)
    __shared__ int res[HB];      // global reservation base within bucket region
    __shared__ int part[STHR];
    __shared__ int stage[CHUNK]; // 64 KB bucket-ordered record staging

    int t = threadIdx.x;
    for (int i = t; i < NB; i += STHR) cnt[i] = 0;
    __syncthreads();

    long s0 = (long)blockIdx.x * CHUNK;
    int end = (int)min((long)CHUNK, (long)E - s0);
    const vint4* pd = reinterpret_cast<const vint4*>(dst + s0);
    const vint4* ps = reinterpret_cast<const vint4*>(src + s0);
    int n4 = end >> 2;

    // ---- phase A: bucket histogram ----
    for (int k = t; k < n4; k += STHR) {
        vint4 d = __builtin_nontemporal_load(pd + k);
        atomicAdd(&cnt[((unsigned)d.x) >> BSH], 1);
        atomicAdd(&cnt[((unsigned)d.y) >> BSH], 1);
        atomicAdd(&cnt[((unsigned)d.z) >> BSH], 1);
        atomicAdd(&cnt[((unsigned)d.w) >> BSH], 1);
    }
    for (int k = (n4 << 2) + t; k < end; k += STHR)
        atomicAdd(&cnt[((unsigned)dst[s0 + k]) >> BSH], 1);
    __syncthreads();

    // ---- phase B: block scan (2 buckets/thread) + bulk global reservation ----
    int b0 = 2 * t, b1 = 2 * t + 1;
    int c0 = (b0 < NB) ? cnt[b0] : 0;
    int c1 = (b1 < NB) ? cnt[b1] : 0;
    part[t] = c0 + c1;
    __syncthreads();
    for (int o = 1; o < STHR; o <<= 1) {
        int pv = (t >= o) ? part[t - o] : 0;
        __syncthreads();
        part[t] += pv;
        __syncthreads();
    }
    int base0 = (t > 0) ? part[t - 1] : 0;
    if (b0 < NB) {
        off[b0] = base0;
        cnt[b0] = base0;                       // cursor for phase C
        res[b0] = c0 ? atomicAdd(&gcur[b0], c0) : 0;
    }
    if (b1 < NB) {
        off[b1] = base0 + c0;
        cnt[b1] = base0 + c0;
        res[b1] = c1 ? atomicAdd(&gcur[b1], c1) : 0;
    }
    if (t == STHR - 1) off[NB] = part[STHR - 1];
    __syncthreads();

    // ---- phase C: place records into LDS staging (bucket-ordered) ----
    for (int k = t; k < n4; k += STHR) {
        vint4 d = __builtin_nontemporal_load(pd + k);
        vint4 s = __builtin_nontemporal_load(ps + k);
        int slot;
        slot = atomicAdd(&cnt[((unsigned)d.x) >> BSH], 1); stage[slot] = ((d.x & BMASK) << 20) | s.x;
        slot = atomicAdd(&cnt[((unsigned)d.y) >> BSH], 1); stage[slot] = ((d.y & BMASK) << 20) | s.y;
        slot = atomicAdd(&cnt[((unsigned)d.z) >> BSH], 1); stage[slot] = ((d.z & BMASK) << 20) | s.z;
        slot = atomicAdd(&cnt[((unsigned)d.w) >> BSH], 1); stage[slot] = ((d.w & BMASK) << 20) | s.w;
    }
    for (int k = (n4 << 2) + t; k < end; k += STHR) {
        int d = dst[s0 + k], s = src[s0 + k];
        int slot = atomicAdd(&cnt[((unsigned)d) >> BSH], 1);
        stage[slot] = ((d & BMASK) << 20) | s;
    }
    __syncthreads();

    // ---- phase D: coalesced flush; bucket of i via binary search in off ----
    for (int i = t; i < end; i += STHR) {
        int lo = 0, hi = NB - 1;
        while (lo < hi) {
            int mid = (lo + hi + 1) >> 1;
            if (off[mid] <= i) lo = mid; else hi = mid - 1;
        }
        long g = (long)lo * C + res[lo] + (i - off[lo]);
        __builtin_nontemporal_store(stage[i], recs + g);
    }
}

// ---- per-bucket deg count -> dinv, v (block per 1024-node bucket) ----
__global__ __launch_bounds__(256) void k_degv(const int* __restrict__ recs,
                                              const int* __restrict__ gcur, int C,
                                              const float* __restrict__ x,
                                              float* __restrict__ dinv,
                                              float* __restrict__ v, int N) {
    __shared__ int c[1024];
    int t = threadIdx.x;
#pragma unroll
    for (int j = 0; j < 4; ++j) c[t + 256 * j] = 0;
    __syncthreads();
    int lo = blockIdx.x * C, hi = lo + gcur[blockIdx.x];
    int i = lo + t;
    for (; i + 768 < hi; i += 1024) {
        int r0 = __builtin_nontemporal_load(recs + i);
        int r1 = __builtin_nontemporal_load(recs + i + 256);
        int r2 = __builtin_nontemporal_load(recs + i + 512);
        int r3 = __builtin_nontemporal_load(recs + i + 768);
        atomicAdd(&c[((unsigned)r0) >> 20], 1);
        atomicAdd(&c[((unsigned)r1) >> 20], 1);
        atomicAdd(&c[((unsigned)r2) >> 20], 1);
        atomicAdd(&c[((unsigned)r3) >> 20], 1);
    }
    for (; i < hi; i += 256)
        atomicAdd(&c[((unsigned)__builtin_nontemporal_load(recs + i)) >> 20], 1);
    __syncthreads();
#pragma unroll
    for (int j = 0; j < 4; ++j) {
        int node = blockIdx.x * 1024 + t + 256 * j;
        if (node < N) {
            float di = rsqrtf((float)c[t + 256 * j] + 1.0f);
            dinv[node] = di;
            v[node] = di * x[node];
        }
    }
}

// ---- layer-1 gather/LDS-scatter + fused MLP -> u ----
__global__ __launch_bounds__(256) void k_gs1(const int* __restrict__ recs,
                                             const int* __restrict__ gcur, int C,
                                             const float* __restrict__ v,
                                             const float* __restrict__ dinv,
                                             const float* __restrict__ W1,
                                             const float* __restrict__ b1,
                                             const float* __restrict__ W2,
                                             float* __restrict__ u, int N) {
    __shared__ float acc[1024];
    int t = threadIdx.x;
#pragma unroll
    for (int j = 0; j < 4; ++j) acc[t + 256 * j] = 0.0f;
    __syncthreads();
    int lo = blockIdx.x * C, hi = lo + gcur[blockIdx.x];
    int i = lo + t;
    for (; i + 768 < hi; i += 1024) {
        int r0 = __builtin_nontemporal_load(recs + i);
        int r1 = __builtin_nontemporal_load(recs + i + 256);
        int r2 = __builtin_nontemporal_load(recs + i + 512);
        int r3 = __builtin_nontemporal_load(recs + i + 768);
        float v0 = v[r0 & 0xFFFFF], v1 = v[r1 & 0xFFFFF];
        float v2 = v[r2 & 0xFFFFF], v3 = v[r3 & 0xFFFFF];
        atomicAdd(&acc[((unsigned)r0) >> 20], v0);
        atomicAdd(&acc[((unsigned)r1) >> 20], v1);
        atomicAdd(&acc[((unsigned)r2) >> 20], v2);
        atomicAdd(&acc[((unsigned)r3) >> 20], v3);
    }
    for (; i < hi; i += 256) {
        int r = __builtin_nontemporal_load(recs + i);
        atomicAdd(&acc[((unsigned)r) >> 20], v[r & 0xFFFFF]);
    }
    __syncthreads();
#pragma unroll
    for (int j = 0; j < 4; ++j) {
        int node = blockIdx.x * 1024 + t + 256 * j;
        if (node < N) {
            float di = dinv[node];
            float at = di * (acc[t + 256 * j] + v[node]);
            float s = 0.0f;
#pragma unroll
            for (int jj = 0; jj < 8; ++jj)
                s += fmaxf(at * W1[jj] + b1[jj], 0.0f) * W2[jj];
            u[node] = di * s;
        }
    }
}

// ---- layer-2 gather/LDS-scatter + fused finalize -> out ----
__global__ __launch_bounds__(256) void k_gs2(const int* __restrict__ recs,
                                             const int* __restrict__ gcur, int C,
                                             const float* __restrict__ u,
                                             const float* __restrict__ dinv,
                                             const float* __restrict__ b2,
                                             float* __restrict__ out, int N) {
    __shared__ float acc[1024];
    int t = threadIdx.x;
#pragma unroll
    for (int j = 0; j < 4; ++j) acc[t + 256 * j] = 0.0f;
    __syncthreads();
    int lo = blockIdx.x * C, hi = lo + gcur[blockIdx.x];
    int i = lo + t;
    for (; i + 768 < hi; i += 1024) {
        int r0 = __builtin_nontemporal_load(recs + i);
        int r1 = __builtin_nontemporal_load(recs + i + 256);
        int r2 = __builtin_nontemporal_load(recs + i + 512);
        int r3 = __builtin_nontemporal_load(recs + i + 768);
        float v0 = u[r0 & 0xFFFFF], v1 = u[r1 & 0xFFFFF];
        float v2 = u[r2 & 0xFFFFF], v3 = u[r3 & 0xFFFFF];
        atomicAdd(&acc[((unsigned)r0) >> 20], v0);
        atomicAdd(&acc[((unsigned)r1) >> 20], v1);
        atomicAdd(&acc[((unsigned)r2) >> 20], v2);
        atomicAdd(&acc[((unsigned)r3) >> 20], v3);
    }
    for (; i < hi; i += 256) {
        int r = __builtin_nontemporal_load(recs + i);
        atomicAdd(&acc[((unsigned)r) >> 20], u[r & 0xFFFFF]);
    }
    __syncthreads();
#pragma unroll
    for (int j = 0; j < 4; ++j) {
        int node = blockIdx.x * 1024 + t + 256 * j;
        if (node < N)
            out[node] = dinv[node] * (acc[t + 256 * j] + u[node]) + b2[0];
    }
}

extern "C" void kernel_launch(void* const* d_in, const int* in_sizes, int n_in,
                              void* d_out, int out_size, void* d_ws, size_t ws_size,
                              hipStream_t stream) {
    const float* x  = (const float*)d_in[0];
    const int*   ei = (const int*)d_in[1];   // [2, E] int32
    const float* W1 = (const float*)d_in[2];
    const float* b1 = (const float*)d_in[3];
    const float* W2 = (const float*)d_in[4];
    const float* b2 = (const float*)d_in[5];
    float* out = (float*)d_out;

    int N = in_sizes[0];
    int E = in_sizes[1] / 2;
    const int* src = ei;
    const int* dst = ei + E;

    int NB = (N + BMASK) >> BSH;             // 1024-node buckets (<= 1024 for N<=2^20)

    // fixed bucket capacity: avg + 8 sigma (Poisson), rounded to 64
    int avg = E / NB;
    int C = avg + 8 * (int)sqrt((double)avg) + 64;
    C = (C + 63) & ~63;
    // clamp to workspace if needed (12MB node arrays + gcur + recs)
    size_t fixed = sizeof(float) * 3ul * N + sizeof(int) * (size_t)NB;
    size_t maxC = (ws_size - fixed) / (sizeof(int) * (size_t)NB);
    if ((size_t)C > maxC) C = (int)maxC;

    char* w = (char*)d_ws;
    float* dinv = (float*)w;  w += sizeof(float) * (size_t)N;
    float* v    = (float*)w;  w += sizeof(float) * (size_t)N;
    float* u    = (float*)w;  w += sizeof(float) * (size_t)N;
    int*   gcur = (int*)w;    w += sizeof(int) * (size_t)NB;
    int*   recs = (int*)w;    // NB * C ints

    int NBLK = (E + CHUNK - 1) / CHUNK;

    k_zero_gcur<<<(NB + 255) / 256, 256, 0, stream>>>(gcur, NB);
    k_sort<<<NBLK, STHR, 0, stream>>>(src, dst, E, NB, C, gcur, recs);
    k_degv<<<NB, 256, 0, stream>>>(recs, gcur, C, x, dinv, v, N);
    k_gs1 <<<NB, 256, 0, stream>>>(recs, gcur, C, v, dinv, W1, b1, W2, u, N);
    k_gs2 <<<NB, 256, 0, stream>>>(recs, gcur, C, u, dinv, b2, out, N);
}

// Round 8
// 346.490 us; speedup vs baseline: 4.6002x; 1.0183x over previous
//
#include <hip/hip_runtime.h>
#include <math.h>

// GCN 2-layer (1->8->1), collapsed + factored + dst-binned (zero global atomics
// on the accumulate paths).
//
// Math (verified):
//   deg[d]  = #edges into d; dinv = rsqrt(deg+1)            (self-loop)
//   v[i]    = dinv[i]*x[i]
//   acc1[d] = sum_e v[src[e]]
//   at[i]   = dinv[i]*(acc1[i] + v[i])
//   u[i]    = dinv[i] * sum_j relu(at[i]*W1[j]+b1[j])*W2[j]
//   out[d]  = dinv[d]*(acc2[d] + u[d]) + b2,  acc2[d] = sum_e u[src[e]]
//
// Structure: fused counting sort (count -> block scan -> bulk reservation ->
// LDS-staged placement -> coalesced flush; WRITE amp measured 1.8x) then
// per-bucket passes over 1024-node LDS windows.
// Record = ((dst&1023)<<20)|src (requires N <= 2^20).
// Round-8: degv/gs1/gs2 at 512 thr/block (15->30 waves/CU) + 8-deep unroll —
// the gather passes are latency-bound (TA floor ~16-20us, measured ~80).

typedef int vint4 __attribute__((ext_vector_type(4)));

#define HB    1024    // bucket capacity in LDS tables (>= NB)
#define STHR  512     // sort block size (8 waves)
#define CHUNK 16384   // edges per sort block
#define BSH   10      // bucket shift (1024 nodes/bucket)
#define BMASK 1023

__global__ void k_zero_gcur(int* __restrict__ gcur, int NB) {
    int i = blockIdx.x * blockDim.x + threadIdx.x;
    if (i < NB) gcur[i] = 0;
}

// ---- fused counting sort: one block per 16K-edge chunk ----
__global__ __launch_bounds__(STHR) void k_sort(const int* __restrict__ src,
                                               const int* __restrict__ dst,
                                               int E, int NB, int C,
                                               int* __restrict__ gcur,
                                               int* __restrict__ recs) {
    __shared__ int cnt[HB];      // phase A: counts; phase C: cursors
    __shared__ int off[HB + 4];  // exclusive within-block offsets (+ off[NB]=end)
    __shared__ int res[HB];      // global reservation base within bucket region
    __shared__ int part[STHR];
    __shared__ int stage[CHUNK]; // 64 KB bucket-ordered record staging

    int t = threadIdx.x;
    for (int i = t; i < NB; i += STHR) cnt[i] = 0;
    __syncthreads();

    long s0 = (long)blockIdx.x * CHUNK;
    int end = (int)min((long)CHUNK, (long)E - s0);
    const vint4* pd = reinterpret_cast<const vint4*>(dst + s0);
    const vint4* ps = reinterpret_cast<const vint4*>(src + s0);
    int n4 = end >> 2;

    // ---- phase A: bucket histogram ----
    for (int k = t; k < n4; k += STHR) {
        vint4 d = __builtin_nontemporal_load(pd + k);
        atomicAdd(&cnt[((unsigned)d.x) >> BSH], 1);
        atomicAdd(&cnt[((unsigned)d.y) >> BSH], 1);
        atomicAdd(&cnt[((unsigned)d.z) >> BSH], 1);
        atomicAdd(&cnt[((unsigned)d.w) >> BSH], 1);
    }
    for (int k = (n4 << 2) + t; k < end; k += STHR)
        atomicAdd(&cnt[((unsigned)dst[s0 + k]) >> BSH], 1);
    __syncthreads();

    // ---- phase B: block scan (2 buckets/thread) + bulk global reservation ----
    int b0 = 2 * t, b1 = 2 * t + 1;
    int c0 = (b0 < NB) ? cnt[b0] : 0;
    int c1 = (b1 < NB) ? cnt[b1] : 0;
    part[t] = c0 + c1;
    __syncthreads();
    for (int o = 1; o < STHR; o <<= 1) {
        int pv = (t >= o) ? part[t - o] : 0;
        __syncthreads();
        part[t] += pv;
        __syncthreads();
    }
    int base0 = (t > 0) ? part[t - 1] : 0;
    if (b0 < NB) {
        off[b0] = base0;
        cnt[b0] = base0;                       // cursor for phase C
        res[b0] = c0 ? atomicAdd(&gcur[b0], c0) : 0;
    }
    if (b1 < NB) {
        off[b1] = base0 + c0;
        cnt[b1] = base0 + c0;
        res[b1] = c1 ? atomicAdd(&gcur[b1], c1) : 0;
    }
    if (t == STHR - 1) off[NB] = part[STHR - 1];
    __syncthreads();

    // ---- phase C: place records into LDS staging (bucket-ordered) ----
    for (int k = t; k < n4; k += STHR) {
        vint4 d = __builtin_nontemporal_load(pd + k);
        vint4 s = __builtin_nontemporal_load(ps + k);
        int slot;
        slot = atomicAdd(&cnt[((unsigned)d.x) >> BSH], 1); stage[slot] = ((d.x & BMASK) << 20) | s.x;
        slot = atomicAdd(&cnt[((unsigned)d.y) >> BSH], 1); stage[slot] = ((d.y & BMASK) << 20) | s.y;
        slot = atomicAdd(&cnt[((unsigned)d.z) >> BSH], 1); stage[slot] = ((d.z & BMASK) << 20) | s.z;
        slot = atomicAdd(&cnt[((unsigned)d.w) >> BSH], 1); stage[slot] = ((d.w & BMASK) << 20) | s.w;
    }
    for (int k = (n4 << 2) + t; k < end; k += STHR) {
        int d = dst[s0 + k], s = src[s0 + k];
        int slot = atomicAdd(&cnt[((unsigned)d) >> BSH], 1);
        stage[slot] = ((d & BMASK) << 20) | s;
    }
    __syncthreads();

    // ---- phase D: coalesced flush; bucket of i via binary search in off ----
    for (int i = t; i < end; i += STHR) {
        int lo = 0, hi = NB - 1;
        while (lo < hi) {
            int mid = (lo + hi + 1) >> 1;
            if (off[mid] <= i) lo = mid; else hi = mid - 1;
        }
        long g = (long)lo * C + res[lo] + (i - off[lo]);
        __builtin_nontemporal_store(stage[i], recs + g);
    }
}

// ---- per-bucket deg count -> dinv, v (512 thr per 1024-node bucket) ----
__global__ __launch_bounds__(512) void k_degv(const int* __restrict__ recs,
                                              const int* __restrict__ gcur, int C,
                                              const float* __restrict__ x,
                                              float* __restrict__ dinv,
                                              float* __restrict__ v, int N) {
    __shared__ int c[1024];
    int t = threadIdx.x;
    c[t] = 0; c[t + 512] = 0;
    __syncthreads();
    int lo = blockIdx.x * C, hi = lo + gcur[blockIdx.x];
    int i = lo + t;
    for (; i + 3584 < hi; i += 4096) {
        int r[8];
#pragma unroll
        for (int j = 0; j < 8; ++j) r[j] = __builtin_nontemporal_load(recs + i + 512 * j);
#pragma unroll
        for (int j = 0; j < 8; ++j) atomicAdd(&c[((unsigned)r[j]) >> 20], 1);
    }
    for (; i < hi; i += 512)
        atomicAdd(&c[((unsigned)__builtin_nontemporal_load(recs + i)) >> 20], 1);
    __syncthreads();
#pragma unroll
    for (int j = 0; j < 2; ++j) {
        int node = blockIdx.x * 1024 + t + 512 * j;
        if (node < N) {
            float di = rsqrtf((float)c[t + 512 * j] + 1.0f);
            dinv[node] = di;
            v[node] = di * x[node];
        }
    }
}

// ---- layer-1 gather/LDS-scatter + fused MLP -> u ----
__global__ __launch_bounds__(512) void k_gs1(const int* __restrict__ recs,
                                             const int* __restrict__ gcur, int C,
                                             const float* __restrict__ v,
                                             const float* __restrict__ dinv,
                                             const float* __restrict__ W1,
                                             const float* __restrict__ b1,
                                             const float* __restrict__ W2,
                                             float* __restrict__ u, int N) {
    __shared__ float acc[1024];
    int t = threadIdx.x;
    acc[t] = 0.0f; acc[t + 512] = 0.0f;
    __syncthreads();
    int lo = blockIdx.x * C, hi = lo + gcur[blockIdx.x];
    int i = lo + t;
    for (; i + 3584 < hi; i += 4096) {
        int r[8]; float vv[8];
#pragma unroll
        for (int j = 0; j < 8; ++j) r[j] = __builtin_nontemporal_load(recs + i + 512 * j);
#pragma unroll
        for (int j = 0; j < 8; ++j) vv[j] = v[r[j] & 0xFFFFF];
#pragma unroll
        for (int j = 0; j < 8; ++j) atomicAdd(&acc[((unsigned)r[j]) >> 20], vv[j]);
    }
    for (; i < hi; i += 512) {
        int r = __builtin_nontemporal_load(recs + i);
        atomicAdd(&acc[((unsigned)r) >> 20], v[r & 0xFFFFF]);
    }
    __syncthreads();
#pragma unroll
    for (int j = 0; j < 2; ++j) {
        int node = blockIdx.x * 1024 + t + 512 * j;
        if (node < N) {
            float di = dinv[node];
            float at = di * (acc[t + 512 * j] + v[node]);
            float s = 0.0f;
#pragma unroll
            for (int jj = 0; jj < 8; ++jj)
                s += fmaxf(at * W1[jj] + b1[jj], 0.0f) * W2[jj];
            u[node] = di * s;
        }
    }
}

// ---- layer-2 gather/LDS-scatter + fused finalize -> out ----
__global__ __launch_bounds__(512) void k_gs2(const int* __restrict__ recs,
                                             const int* __restrict__ gcur, int C,
                                             const float* __restrict__ u,
                                             const float* __restrict__ dinv,
                                             const float* __restrict__ b2,
                                             float* __restrict__ out, int N) {
    __shared__ float acc[1024];
    int t = threadIdx.x;
    acc[t] = 0.0f; acc[t + 512] = 0.0f;
    __syncthreads();
    int lo = blockIdx.x * C, hi = lo + gcur[blockIdx.x];
    int i = lo + t;
    for (; i + 3584 < hi; i += 4096) {
        int r[8]; float vv[8];
#pragma unroll
        for (int j = 0; j < 8; ++j) r[j] = __builtin_nontemporal_load(recs + i + 512 * j);
#pragma unroll
        for (int j = 0; j < 8; ++j) vv[j] = u[r[j] & 0xFFFFF];
#pragma unroll
        for (int j = 0; j < 8; ++j) atomicAdd(&acc[((unsigned)r[j]) >> 20], vv[j]);
    }
    for (; i < hi; i += 512) {
        int r = __builtin_nontemporal_load(recs + i);
        atomicAdd(&acc[((unsigned)r) >> 20], u[r & 0xFFFFF]);
    }
    __syncthreads();
#pragma unroll
    for (int j = 0; j < 2; ++j) {
        int node = blockIdx.x * 1024 + t + 512 * j;
        if (node < N)
            out[node] = dinv[node] * (acc[t + 512 * j] + u[node]) + b2[0];
    }
}

extern "C" void kernel_launch(void* const* d_in, const int* in_sizes, int n_in,
                              void* d_out, int out_size, void* d_ws, size_t ws_size,
                              hipStream_t stream) {
    const float* x  = (const float*)d_in[0];
    const int*   ei = (const int*)d_in[1];   // [2, E] int32
    const float* W1 = (const float*)d_in[2];
    const float* b1 = (const float*)d_in[3];
    const float* W2 = (const float*)d_in[4];
    const float* b2 = (const float*)d_in[5];
    float* out = (float*)d_out;

    int N = in_sizes[0];
    int E = in_sizes[1] / 2;
    const int* src = ei;
    const int* dst = ei + E;

    int NB = (N + BMASK) >> BSH;             // 1024-node buckets (<= 1024 for N<=2^20)

    // fixed bucket capacity: avg + 8 sigma (Poisson), rounded to 64
    int avg = E / NB;
    int C = avg + 8 * (int)sqrt((double)avg) + 64;
    C = (C + 63) & ~63;
    size_t fixed = sizeof(float) * 3ul * N + sizeof(int) * (size_t)NB;
    size_t maxC = (ws_size - fixed) / (sizeof(int) * (size_t)NB);
    if ((size_t)C > maxC) C = (int)maxC;

    char* w = (char*)d_ws;
    float* dinv = (float*)w;  w += sizeof(float) * (size_t)N;
    float* v    = (float*)w;  w += sizeof(float) * (size_t)N;
    float* u    = (float*)w;  w += sizeof(float) * (size_t)N;
    int*   gcur = (int*)w;    w += sizeof(int) * (size_t)NB;
    int*   recs = (int*)w;    // NB * C ints

    int NBLK = (E + CHUNK - 1) / CHUNK;

    k_zero_gcur<<<(NB + 255) / 256, 256, 0, stream>>>(gcur, NB);
    k_sort<<<NBLK, STHR, 0, stream>>>(src, dst, E, NB, C, gcur, recs);
    k_degv<<<NB, 512, 0, stream>>>(recs, gcur, C, x, dinv, v, N);
    k_gs1 <<<NB, 512, 0, stream>>>(recs, gcur, C, v, dinv, W1, b1, W2, u, N);
    k_gs2 <<<NB, 512, 0, stream>>>(recs, gcur, C, u, dinv, b2, out, N);
}

// Round 9
// 326.572 us; speedup vs baseline: 4.8808x; 1.0610x over previous
//
#include <hip/hip_runtime.h>
#include <math.h>

// GCN 2-layer (1->8->1), collapsed + factored + dst-binned (zero global atomics
// on the accumulate paths).
//
// Math (verified):
//   deg[d]  = #edges into d; dinv = rsqrt(deg+1)            (self-loop)
//   v[i]    = dinv[i]*x[i]                                  (stored fp16)
//   acc1[d] = sum_e v[src[e]]
//   at[i]   = dinv[i]*(acc1[i] + v[i])
//   u[i]    = dinv[i] * sum_j relu(at[i]*W1[j]+b1[j])*W2[j] (stored fp16)
//   out[d]  = dinv[d]*(acc2[d] + u[d]) + b2,  acc2[d] = sum_e u[src[e]]
//
// Round-9: (1) v/u in fp16 — the per-pass random gather footprint drops
// 4MB->2MB so it fits per-XCD L2 beside the streams (round-8 showed the
// gather passes are throughput-ceiling-bound: waves/ILP x2 -> no change;
// model: L2 misses -> 64B IF line fills ~ 640MB/pass).
// (2) k_sort phase-D binary search replaced by slot2b LDS table
// (~27us VALU -> ~2). Record = ((dst&1023)<<20)|src (requires N <= 2^20).

typedef int vint4 __attribute__((ext_vector_type(4)));

#define HB    1024    // bucket capacity in LDS tables (>= NB)
#define STHR  512     // sort block size (8 waves)
#define CHUNK 16384   // edges per sort block
#define BSH   10      // bucket shift (1024 nodes/bucket)
#define BMASK 1023

__global__ void k_zero_gcur(int* __restrict__ gcur, int NB) {
    int i = blockIdx.x * blockDim.x + threadIdx.x;
    if (i < NB) gcur[i] = 0;
}

// ---- fused counting sort: one block per 16K-edge chunk ----
__global__ __launch_bounds__(STHR) void k_sort(const int* __restrict__ src,
                                               const int* __restrict__ dst,
                                               int E, int NB, int C,
                                               int* __restrict__ gcur,
                                               int* __restrict__ recs) {
    __shared__ int cnt[HB];            // phase A: counts; phase C: cursors
    __shared__ int off[HB + 4];        // exclusive within-block offsets
    __shared__ int res[HB];            // res2[b] = C*b + gbase[b] - off[b]
    __shared__ int part[STHR];
    __shared__ int stage[CHUNK];       // 64 KB bucket-ordered record staging
    __shared__ unsigned short s2b[CHUNK]; // 32 KB slot -> bucket

    int t = threadIdx.x;
    for (int i = t; i < NB; i += STHR) cnt[i] = 0;
    __syncthreads();

    long s0 = (long)blockIdx.x * CHUNK;
    int end = (int)min((long)CHUNK, (long)E - s0);
    const vint4* pd = reinterpret_cast<const vint4*>(dst + s0);
    const vint4* ps = reinterpret_cast<const vint4*>(src + s0);
    int n4 = end >> 2;

    // ---- phase A: bucket histogram ----
    for (int k = t; k < n4; k += STHR) {
        vint4 d = __builtin_nontemporal_load(pd + k);
        atomicAdd(&cnt[((unsigned)d.x) >> BSH], 1);
        atomicAdd(&cnt[((unsigned)d.y) >> BSH], 1);
        atomicAdd(&cnt[((unsigned)d.z) >> BSH], 1);
        atomicAdd(&cnt[((unsigned)d.w) >> BSH], 1);
    }
    for (int k = (n4 << 2) + t; k < end; k += STHR)
        atomicAdd(&cnt[((unsigned)dst[s0 + k]) >> BSH], 1);
    __syncthreads();

    // ---- phase B: block scan (2 buckets/thread) + bulk global reservation ----
    int b0 = 2 * t, b1 = 2 * t + 1;
    int c0 = (b0 < NB) ? cnt[b0] : 0;
    int c1 = (b1 < NB) ? cnt[b1] : 0;
    part[t] = c0 + c1;
    __syncthreads();
    for (int o = 1; o < STHR; o <<= 1) {
        int pv = (t >= o) ? part[t - o] : 0;
        __syncthreads();
        part[t] += pv;
        __syncthreads();
    }
    int base0 = (t > 0) ? part[t - 1] : 0;
    if (b0 < NB) {
        off[b0] = base0;
        cnt[b0] = base0;                       // cursor for phase C
        int r0 = c0 ? atomicAdd(&gcur[b0], c0) : 0;
        res[b0] = b0 * C + r0 - base0;         // res2
    }
    if (b1 < NB) {
        int o1 = base0 + c0;
        off[b1] = o1;
        cnt[b1] = o1;
        int r1 = c1 ? atomicAdd(&gcur[b1], c1) : 0;
        res[b1] = b1 * C + r1 - o1;            // res2
    }
    __syncthreads();

    // ---- phase C: place records into LDS staging (bucket-ordered) ----
    for (int k = t; k < n4; k += STHR) {
        vint4 d = __builtin_nontemporal_load(pd + k);
        vint4 s = __builtin_nontemporal_load(ps + k);
        int b, slot;
        b = ((unsigned)d.x) >> BSH; slot = atomicAdd(&cnt[b], 1);
        stage[slot] = ((d.x & BMASK) << 20) | s.x; s2b[slot] = (unsigned short)b;
        b = ((unsigned)d.y) >> BSH; slot = atomicAdd(&cnt[b], 1);
        stage[slot] = ((d.y & BMASK) << 20) | s.y; s2b[slot] = (unsigned short)b;
        b = ((unsigned)d.z) >> BSH; slot = atomicAdd(&cnt[b], 1);
        stage[slot] = ((d.z & BMASK) << 20) | s.z; s2b[slot] = (unsigned short)b;
        b = ((unsigned)d.w) >> BSH; slot = atomicAdd(&cnt[b], 1);
        stage[slot] = ((d.w & BMASK) << 20) | s.w; s2b[slot] = (unsigned short)b;
    }
    for (int k = (n4 << 2) + t; k < end; k += STHR) {
        int d = dst[s0 + k], s = src[s0 + k];
        int b = ((unsigned)d) >> BSH;
        int slot = atomicAdd(&cnt[b], 1);
        stage[slot] = ((d & BMASK) << 20) | s;
        s2b[slot] = (unsigned short)b;
    }
    __syncthreads();

    // ---- phase D: coalesced flush, direct address ----
    for (int i = t; i < end; i += STHR) {
        int b = s2b[i];
        __builtin_nontemporal_store(stage[i], recs + (long)(res[b] + i));
    }
}

// ---- per-bucket deg count -> dinv, v(fp16) ----
__global__ __launch_bounds__(512) void k_degv(const int* __restrict__ recs,
                                              const int* __restrict__ gcur, int C,
                                              const float* __restrict__ x,
                                              float* __restrict__ dinv,
                                              _Float16* __restrict__ v, int N) {
    __shared__ int c[1024];
    int t = threadIdx.x;
    c[t] = 0; c[t + 512] = 0;
    __syncthreads();
    int lo = blockIdx.x * C;
    int cnt_ = gcur[blockIdx.x];
    int n4 = cnt_ >> 2;
    const vint4* p = reinterpret_cast<const vint4*>(recs + lo);
    for (int k = t; k < n4; k += 512) {
        vint4 r = __builtin_nontemporal_load(p + k);
        atomicAdd(&c[((unsigned)r.x) >> 20], 1);
        atomicAdd(&c[((unsigned)r.y) >> 20], 1);
        atomicAdd(&c[((unsigned)r.z) >> 20], 1);
        atomicAdd(&c[((unsigned)r.w) >> 20], 1);
    }
    for (int k = (n4 << 2) + t; k < cnt_; k += 512)
        atomicAdd(&c[((unsigned)__builtin_nontemporal_load(recs + lo + k)) >> 20], 1);
    __syncthreads();
#pragma unroll
    for (int j = 0; j < 2; ++j) {
        int node = blockIdx.x * 1024 + t + 512 * j;
        if (node < N) {
            float di = rsqrtf((float)c[t + 512 * j] + 1.0f);
            dinv[node] = di;
            v[node] = (_Float16)(di * x[node]);
        }
    }
}

// ---- layer-1 gather/LDS-scatter + fused MLP -> u(fp16) ----
__global__ __launch_bounds__(512) void k_gs1(const int* __restrict__ recs,
                                             const int* __restrict__ gcur, int C,
                                             const _Float16* __restrict__ v,
                                             const float* __restrict__ dinv,
                                             const float* __restrict__ W1,
                                             const float* __restrict__ b1,
                                             const float* __restrict__ W2,
                                             _Float16* __restrict__ u, int N) {
    __shared__ float acc[1024];
    int t = threadIdx.x;
    acc[t] = 0.0f; acc[t + 512] = 0.0f;
    __syncthreads();
    int lo = blockIdx.x * C;
    int cnt_ = gcur[blockIdx.x];
    int n4 = cnt_ >> 2;
    const vint4* p = reinterpret_cast<const vint4*>(recs + lo);
    for (int k = t; k + 512 < n4; k += 1024) {
        vint4 ra = __builtin_nontemporal_load(p + k);
        vint4 rb = __builtin_nontemporal_load(p + k + 512);
        float va0 = (float)v[ra.x & 0xFFFFF], va1 = (float)v[ra.y & 0xFFFFF];
        float va2 = (float)v[ra.z & 0xFFFFF], va3 = (float)v[ra.w & 0xFFFFF];
        float vb0 = (float)v[rb.x & 0xFFFFF], vb1 = (float)v[rb.y & 0xFFFFF];
        float vb2 = (float)v[rb.z & 0xFFFFF], vb3 = (float)v[rb.w & 0xFFFFF];
        atomicAdd(&acc[((unsigned)ra.x) >> 20], va0);
        atomicAdd(&acc[((unsigned)ra.y) >> 20], va1);
        atomicAdd(&acc[((unsigned)ra.z) >> 20], va2);
        atomicAdd(&acc[((unsigned)ra.w) >> 20], va3);
        atomicAdd(&acc[((unsigned)rb.x) >> 20], vb0);
        atomicAdd(&acc[((unsigned)rb.y) >> 20], vb1);
        atomicAdd(&acc[((unsigned)rb.z) >> 20], vb2);
        atomicAdd(&acc[((unsigned)rb.w) >> 20], vb3);
    }
    int k4 = ((n4 - ((n4 / 1024) * 1024 >= n4 ? 0 : 0)) , 0); (void)k4;
    // tail over remaining quads
    int done4 = (n4 / 1024) * 1024;
    // redo the last partial region: quads in [done4, n4) not covered by pairs
    for (int k = done4 + t; k < n4; k += 512) {
        // skip quads already processed by the paired loop: pairs covered [k0, k0+1024)
        // the paired loop processed quads k with k+512 < n4 in strides; to stay exact,
        // the paired loop above only ran full 1024-strides from t; recompute coverage:
        // covered iterations: k = t + 1024*m while k + 512 < n4 -> both k and k+512.
        bool covered = false;
        int rel = k - (k % 1024 >= 512 ? 512 : 0);
        (void)rel;
        // conservative: determine directly
        int base = k % 1024;
        int start = k - base + (base % 512) ; (void)start;
        covered = false;
        {
            int kk = k % 1024;
            int m = k / 1024;
            int first = m * 1024 + (kk % 512);
            if (first + 512 < n4 && (kk < 512 ? first == k : first + 512 == k)) covered = true;
        }
        if (covered) continue;
        vint4 r = __builtin_nontemporal_load(p + k);
        atomicAdd(&acc[((unsigned)r.x) >> 20], (float)v[r.x & 0xFFFFF]);
        atomicAdd(&acc[((unsigned)r.y) >> 20], (float)v[r.y & 0xFFFFF]);
        atomicAdd(&acc[((unsigned)r.z) >> 20], (float)v[r.z & 0xFFFFF]);
        atomicAdd(&acc[((unsigned)r.w) >> 20], (float)v[r.w & 0xFFFFF]);
    }
    for (int k = (n4 << 2) + t; k < cnt_; k += 512) {
        int r = __builtin_nontemporal_load(recs + lo + k);
        atomicAdd(&acc[((unsigned)r) >> 20], (float)v[r & 0xFFFFF]);
    }
    __syncthreads();
#pragma unroll
    for (int j = 0; j < 2; ++j) {
        int node = blockIdx.x * 1024 + t + 512 * j;
        if (node < N) {
            float di = dinv[node];
            float at = di * (acc[t + 512 * j] + (float)v[node]);
            float s = 0.0f;
#pragma unroll
            for (int jj = 0; jj < 8; ++jj)
                s += fmaxf(at * W1[jj] + b1[jj], 0.0f) * W2[jj];
            u[node] = (_Float16)(di * s);
        }
    }
}

// ---- layer-2 gather/LDS-scatter + fused finalize -> out ----
__global__ __launch_bounds__(512) void k_gs2(const int* __restrict__ recs,
                                             const int* __restrict__ gcur, int C,
                                             const _Float16* __restrict__ u,
                                             const float* __restrict__ dinv,
                                             const float* __restrict__ b2,
                                             float* __restrict__ out, int N) {
    __shared__ float acc[1024];
    int t = threadIdx.x;
    acc[t] = 0.0f; acc[t + 512] = 0.0f;
    __syncthreads();
    int lo = blockIdx.x * C;
    int cnt_ = gcur[blockIdx.x];
    int n4 = cnt_ >> 2;
    const vint4* p = reinterpret_cast<const vint4*>(recs + lo);
    for (int k = t; k < n4; k += 512) {
        vint4 r = __builtin_nontemporal_load(p + k);
        float v0 = (float)u[r.x & 0xFFFFF], v1 = (float)u[r.y & 0xFFFFF];
        float v2 = (float)u[r.z & 0xFFFFF], v3 = (float)u[r.w & 0xFFFFF];
        atomicAdd(&acc[((unsigned)r.x) >> 20], v0);
        atomicAdd(&acc[((unsigned)r.y) >> 20], v1);
        atomicAdd(&acc[((unsigned)r.z) >> 20], v2);
        atomicAdd(&acc[((unsigned)r.w) >> 20], v3);
    }
    for (int k = (n4 << 2) + t; k < cnt_; k += 512) {
        int r = __builtin_nontemporal_load(recs + lo + k);
        atomicAdd(&acc[((unsigned)r) >> 20], (float)u[r & 0xFFFFF]);
    }
    __syncthreads();
#pragma unroll
    for (int j = 0; j < 2; ++j) {
        int node = blockIdx.x * 1024 + t + 512 * j;
        if (node < N)
            out[node] = dinv[node] * (acc[t + 512 * j] + (float)u[node]) + b2[0];
    }
}

extern "C" void kernel_launch(void* const* d_in, const int* in_sizes, int n_in,
                              void* d_out, int out_size, void* d_ws, size_t ws_size,
                              hipStream_t stream) {
    const float* x  = (const float*)d_in[0];
    const int*   ei = (const int*)d_in[1];   // [2, E] int32
    const float* W1 = (const float*)d_in[2];
    const float* b1 = (const float*)d_in[3];
    const float* W2 = (const float*)d_in[4];
    const float* b2 = (const float*)d_in[5];
    float* out = (float*)d_out;

    int N = in_sizes[0];
    int E = in_sizes[1] / 2;
    const int* src = ei;
    const int* dst = ei + E;

    int NB = (N + BMASK) >> BSH;             // 1024-node buckets (<= 1024 for N<=2^20)

    // fixed bucket capacity: avg + 8 sigma (Poisson), rounded to 64
    int avg = E / NB;
    int C = avg + 8 * (int)sqrt((double)avg) + 64;
    C = (C + 63) & ~63;
    size_t fixed = sizeof(float) * (size_t)N + sizeof(_Float16) * 2ul * N
                 + sizeof(int) * (size_t)NB;
    size_t maxC = (ws_size - fixed) / (sizeof(int) * (size_t)NB);
    if ((size_t)C > maxC) C = (int)maxC;

    char* w = (char*)d_ws;
    float*    dinv = (float*)w;     w += sizeof(float) * (size_t)N;
    _Float16* v    = (_Float16*)w;  w += sizeof(_Float16) * (size_t)N;
    _Float16* u    = (_Float16*)w;  w += sizeof(_Float16) * (size_t)N;
    int*      gcur = (int*)w;       w += sizeof(int) * (size_t)NB;
    int*      recs = (int*)w;       // NB * C ints

    int NBLK = (E + CHUNK - 1) / CHUNK;

    k_zero_gcur<<<(NB + 255) / 256, 256, 0, stream>>>(gcur, NB);
    k_sort<<<NBLK, STHR, 0, stream>>>(src, dst, E, NB, C, gcur, recs);
    k_degv<<<NB, 512, 0, stream>>>(recs, gcur, C, x, dinv, v, N);
    k_gs1 <<<NB, 512, 0, stream>>>(recs, gcur, C, v, dinv, W1, b1, W2, u, N);
    k_gs2 <<<NB, 512, 0, stream>>>(recs, gcur, C, u, dinv, b2, out, N);
}